// Round 1
// baseline (815.234 us; speedup 1.0000x reference)
//
#include <hip/hip_runtime.h>
#include <hip/hip_bf16.h>

#define DEV __device__ __forceinline__

static constexpr int TBE = 16;   // batch elements per block
static constexpr int NTH = 512;  // 8 waves; each wave owns 2 elements

DEV void wsync() { asm volatile("s_waitcnt lgkmcnt(0)" ::: "memory"); }

DEV unsigned short f2bf(float f) {
  unsigned u = __float_as_uint(f);
  unsigned r = (u + 0x7fffu + ((u >> 16) & 1u)) >> 16;
  return (unsigned short)r;
}

// Cooperative load of a 128x128 f32 tile into LDS, XOR-swizzled on 16B slots
// (slot = j*32 + (g ^ (j&7))) so per-lane row reads are bank-conflict-free.
DEV void load_w128(const float* __restrict__ g, int rowStride, int colOff,
                   float4* __restrict__ wbuf, int tid) {
#pragma unroll
  for (int i = 0; i < 8; ++i) {
    int f = i * NTH + tid;          // 4096 float4 tiles
    int j = f >> 5, gg = f & 31;
    float4 v = *(const float4*)(g + (size_t)j * rowStride + colOff + gg * 4);
    wbuf[(j << 5) | (gg ^ (j & 7))] = v;
  }
}

// out[j] = sum_k act[e][k] * W[j][k]; lane owns j0=lane and j1=lane+64,
// E rows batched per weight fetch (acts are LDS broadcast reads).
template <int E>
DEV void matvec_f32(const float* act, int rs, const float4* w, int j0,
                    float* acc0, float* acc1) {
  const int sw = j0 & 7;
  const float4* w0p = w + (j0 << 5);
  const float4* w1p = w + ((j0 + 64) << 5);
#pragma unroll 4
  for (int g = 0; g < 32; ++g) {
    float4 w0 = w0p[g ^ sw];
    float4 w1 = w1p[g ^ sw];
#pragma unroll
    for (int e = 0; e < E; ++e) {
      float4 a = *(const float4*)(act + e * rs + (g << 2));
      acc0[e] = fmaf(a.x, w0.x, acc0[e]); acc0[e] = fmaf(a.y, w0.y, acc0[e]);
      acc0[e] = fmaf(a.z, w0.z, acc0[e]); acc0[e] = fmaf(a.w, w0.w, acc0[e]);
      acc1[e] = fmaf(a.x, w1.x, acc1[e]); acc1[e] = fmaf(a.y, w1.y, acc1[e]);
      acc1[e] = fmaf(a.z, w1.z, acc1[e]); acc1[e] = fmaf(a.w, w1.w, acc1[e]);
    }
  }
}

template <int E>
DEV void matvec_bf16(const unsigned short* act, int rs, const float4* w, int j0,
                     float* acc0, float* acc1) {
  const int sw = j0 & 7;
  const float4* w0p = w + (j0 << 5);
  const float4* w1p = w + ((j0 + 64) << 5);
#pragma unroll 4
  for (int g = 0; g < 32; ++g) {
    float4 w0 = w0p[g ^ sw];
    float4 w1 = w1p[g ^ sw];
#pragma unroll
    for (int e = 0; e < E; ++e) {
      uint2 u = *(const uint2*)(act + e * rs + (g << 2));
      float ax = __uint_as_float(u.x << 16);
      float ay = __uint_as_float(u.x & 0xffff0000u);
      float az = __uint_as_float(u.y << 16);
      float aw = __uint_as_float(u.y & 0xffff0000u);
      acc0[e] = fmaf(ax, w0.x, acc0[e]); acc0[e] = fmaf(ay, w0.y, acc0[e]);
      acc0[e] = fmaf(az, w0.z, acc0[e]); acc0[e] = fmaf(aw, w0.w, acc0[e]);
      acc1[e] = fmaf(ax, w1.x, acc1[e]); acc1[e] = fmaf(ay, w1.y, acc1[e]);
      acc1[e] = fmaf(az, w1.z, acc1[e]); acc1[e] = fmaf(aw, w1.w, acc1[e]);
    }
  }
}

// LayerNorm over 128 values held as 2/lane across one wave (intra-wave only).
DEV void wave_ln(float& v0, float& v1, float g0, float g1, float b0, float b1) {
  float s = v0 + v1;
  float q = fmaf(v0, v0, v1 * v1);
#pragma unroll
  for (int off = 32; off >= 1; off >>= 1) {
    s += __shfl_xor(s, off, 64);
    q += __shfl_xor(q, off, 64);
  }
  float mean = s * 0.0078125f;
  float var = fmaf(q, 0.0078125f, -mean * mean);
  float r = rsqrtf(var + 1e-5f);
  v0 = fmaf((v0 - mean) * r, g0, b0);
  v1 = fmaf((v1 - mean) * r, g1, b1);
}

__global__ __launch_bounds__(NTH, 2)
void gcn_fused(const float* __restrict__ cur_x,
               const float* __restrict__ nb_x,
               const int* __restrict__ nb_mask,
               const float* __restrict__ enc_w1, const float* __restrict__ enc_b1,
               const float* __restrict__ enc_g1, const float* __restrict__ enc_be1,
               const float* __restrict__ enc_w2, const float* __restrict__ enc_b2,
               const float* __restrict__ enc_g2, const float* __restrict__ enc_be2,
               const float* __restrict__ in_proj_w, const float* __restrict__ in_proj_b,
               const float* __restrict__ out_w, const float* __restrict__ out_b,
               const float* __restrict__ an_g, const float* __restrict__ an_b,
               const float* __restrict__ p1_w, const float* __restrict__ p1_b,
               const float* __restrict__ p1_g, const float* __restrict__ p1_be,
               const float* __restrict__ p2_w, const float* __restrict__ p2_b,
               const float* __restrict__ p2_g, const float* __restrict__ p2_be,
               float* __restrict__ out)
{
  __shared__ float4 s_w[128 * 32];                 // 64 KB stage weights (swizzled)
  __shared__ float  s_w1t[16 * 128];               // 8 KB w1 transposed [k][j]
  __shared__ float  s_x[8][4][16];                 // per-wave input rows
  __shared__ float  s_h1[8][4][128];               // per-wave enc1 outputs
  __shared__ float  s_cur[TBE][128];               // cur_emb (f32)
  __shared__ unsigned short s_nb[TBE][8][128];     // nb_emb (bf16)
  __shared__ float  s_ctx[TBE][128];               // ctx, later reused for h
  __shared__ float  s_agg[TBE][128];               // agg

  const int tid = threadIdx.x;
  const int wv = tid >> 6;
  const int lane = tid & 63;
  const int j0 = lane;
  const int j1 = lane + 64;
  const int ebase = blockIdx.x * TBE;
  const int le0 = wv * 2;          // this wave's 2 local elements
  const int ge0 = ebase + le0;

  // ---------- encoder stage (w1 + w2 resident) ----------
  for (int i = tid; i < 2048; i += NTH) {
    int j = i & 127, k = i >> 7;
    s_w1t[k * 128 + j] = enc_w1[j * 16 + k];
  }
  load_w128(enc_w2, 128, 0, s_w, tid);
  __syncthreads();

  const float b1a = enc_b1[j0], b1b = enc_b1[j1];
  const float g1a = enc_g1[j0], g1b = enc_g1[j1];
  const float e1a = enc_be1[j0], e1b = enc_be1[j1];
  const float b2a = enc_b2[j0], b2b = enc_b2[j1];
  const float g2a = enc_g2[j0], g2b = enc_g2[j1];
  const float e2a = enc_be2[j0], e2b = enc_be2[j1];

  // 18 rows per wave (2 elems x (1 cur + 8 nb)), groups of 4 (last 2 dummy).
#pragma unroll 1
  for (int grp = 0; grp < 5; ++grp) {
    const int r0 = grp * 4;
    {
      int rr = lane >> 4, kk = lane & 15;
      int lr = r0 + rr; if (lr > 17) lr = 17;
      int el = (lr >= 9) ? 1 : 0;
      int kind = lr - el * 9;
      int ge = ge0 + el;
      const float* src = (kind == 0) ? (cur_x + (size_t)ge * 16)
                                     : (nb_x + ((size_t)ge * 8 + (kind - 1)) * 16);
      s_x[wv][rr][kk] = src[kk];
    }
    wsync();
    float a0[4], a1[4];
#pragma unroll
    for (int e = 0; e < 4; ++e) { a0[e] = b1a; a1[e] = b1b; }
#pragma unroll
    for (int k = 0; k < 16; ++k) {
      float w0 = s_w1t[k * 128 + j0];
      float w1v = s_w1t[k * 128 + j1];
#pragma unroll
      for (int e = 0; e < 4; ++e) {
        float a = s_x[wv][e][k];
        a0[e] = fmaf(a, w0, a0[e]);
        a1[e] = fmaf(a, w1v, a1[e]);
      }
    }
#pragma unroll
    for (int e = 0; e < 4; ++e) {
      wave_ln(a0[e], a1[e], g1a, g1b, e1a, e1b);
      a0[e] = fmaxf(a0[e], 0.f);
      a1[e] = fmaxf(a1[e], 0.f);
      s_h1[wv][e][j0] = a0[e];
      s_h1[wv][e][j1] = a1[e];
    }
    wsync();
    float o0[4], o1[4];
#pragma unroll
    for (int e = 0; e < 4; ++e) { o0[e] = b2a; o1[e] = b2b; }
    matvec_f32<4>(&s_h1[wv][0][0], 128, s_w, j0, o0, o1);
#pragma unroll
    for (int e = 0; e < 4; ++e) {
      wave_ln(o0[e], o1[e], g2a, g2b, e2a, e2b);
      int lr = r0 + e;
      if (lr <= 17) {
        int el = (lr >= 9) ? 1 : 0;
        int kind = lr - el * 9;
        int l = le0 + el;
        if (kind == 0) { s_cur[l][j0] = o0[e]; s_cur[l][j1] = o1[e]; }
        else { s_nb[l][kind - 1][j0] = f2bf(o0[e]); s_nb[l][kind - 1][j1] = f2bf(o1[e]); }
      }
    }
  }

  // neighbor masks (wave-uniform broadcast loads)
  int mbits[2];
#pragma unroll
  for (int el = 0; el < 2; ++el) {
    int m = 0;
#pragma unroll
    for (int n = 0; n < 8; ++n)
      m |= (nb_mask[(size_t)(ge0 + el) * 8 + n] > 0) ? (1 << n) : 0;
    mbits[el] = m;
  }

  // ---------- q projection ----------
  __syncthreads();
  load_w128(in_proj_w, 128, 0, s_w, tid);
  __syncthreads();
  float q0[2], q1[2];
  {
    const float bq0 = in_proj_b[j0], bq1 = in_proj_b[j1];
    q0[0] = q0[1] = bq0; q1[0] = q1[1] = bq1;
    matvec_f32<2>(&s_cur[le0][0], 128, s_w, j0, q0, q1);
  }

  // ---------- k + scores + softmax ----------
  __syncthreads();
  load_w128(in_proj_w + 128 * 128, 128, 0, s_w, tid);
  __syncthreads();
  float aA[2][8], aB[2][8];
  {
    const float bk0 = in_proj_b[128 + j0], bk1 = in_proj_b[128 + j1];
#pragma unroll
    for (int el = 0; el < 2; ++el) {
      float sA[8], sB[8];
#pragma unroll
      for (int h = 0; h < 2; ++h) {
        float k0[4], k1[4];
#pragma unroll
        for (int e = 0; e < 4; ++e) { k0[e] = bk0; k1[e] = bk1; }
        matvec_bf16<4>(&s_nb[le0 + el][h * 4][0], 128, s_w, j0, k0, k1);
#pragma unroll
        for (int e = 0; e < 4; ++e) {
          float p0 = q0[el] * k0[e];
          float p1 = q1[el] * k1[e];
#pragma unroll
          for (int off = 16; off >= 1; off >>= 1) {   // reduce within 32-lane head groups
            p0 += __shfl_xor(p0, off, 64);
            p1 += __shfl_xor(p1, off, 64);
          }
          sA[h * 4 + e] = p0 * 0.17677669529663687f;  // 1/sqrt(32)
          sB[h * 4 + e] = p1 * 0.17677669529663687f;
        }
      }
      int m = mbits[el];
      if (m != 0) {
        float mA = -1e30f, mB = -1e30f;
#pragma unroll
        for (int n = 0; n < 8; ++n) if ((m >> n) & 1) { mA = fmaxf(mA, sA[n]); mB = fmaxf(mB, sB[n]); }
        float dA = 0.f, dB = 0.f;
#pragma unroll
        for (int n = 0; n < 8; ++n) {
          float eA = ((m >> n) & 1) ? __expf(sA[n] - mA) : 0.f;
          float eB = ((m >> n) & 1) ? __expf(sB[n] - mB) : 0.f;
          aA[el][n] = eA; aB[el][n] = eB; dA += eA; dB += eB;
        }
        float rA = 1.f / dA, rB = 1.f / dB;
#pragma unroll
        for (int n = 0; n < 8; ++n) { aA[el][n] *= rA; aB[el][n] *= rB; }
      } else {
#pragma unroll
        for (int n = 0; n < 8; ++n) { aA[el][n] = 0.f; aB[el][n] = 0.f; }
      }
    }
  }

  // ---------- v + context ----------
  __syncthreads();
  load_w128(in_proj_w + 2 * 128 * 128, 128, 0, s_w, tid);
  __syncthreads();
  {
    const float bv0 = in_proj_b[256 + j0], bv1 = in_proj_b[256 + j1];
#pragma unroll
    for (int el = 0; el < 2; ++el) {
      float c0 = 0.f, c1 = 0.f;
#pragma unroll
      for (int h = 0; h < 2; ++h) {
        float v0[4], v1[4];
#pragma unroll
        for (int e = 0; e < 4; ++e) { v0[e] = bv0; v1[e] = bv1; }
        matvec_bf16<4>(&s_nb[le0 + el][h * 4][0], 128, s_w, j0, v0, v1);
#pragma unroll
        for (int e = 0; e < 4; ++e) {
          c0 = fmaf(aA[el][h * 4 + e], v0[e], c0);
          c1 = fmaf(aB[el][h * 4 + e], v1[e], c1);
        }
      }
      s_ctx[le0 + el][j0] = c0;
      s_ctx[le0 + el][j1] = c1;
    }
  }

  // ---------- out proj + attn LN + agg select ----------
  __syncthreads();
  load_w128(out_w, 128, 0, s_w, tid);
  __syncthreads();
  {
    const float bo0 = out_b[j0], bo1 = out_b[j1];
    const float ga0 = an_g[j0], ga1 = an_g[j1];
    const float bb0 = an_b[j0], bb1 = an_b[j1];
    float o0[2], o1[2];
    o0[0] = o0[1] = bo0; o1[0] = o1[1] = bo1;
    matvec_f32<2>(&s_ctx[le0][0], 128, s_w, j0, o0, o1);
#pragma unroll
    for (int el = 0; el < 2; ++el) {
      wave_ln(o0[el], o1[el], ga0, ga1, bb0, bb1);
      bool h = mbits[el] != 0;
      float A0 = h ? o0[el] : s_cur[le0 + el][j0];
      float A1 = h ? o1[el] : s_cur[le0 + el][j1];
      s_agg[le0 + el][j0] = A0;
      s_agg[le0 + el][j1] = A1;
    }
  }

  // ---------- p1 (two 128-col halves: cur part + agg part) ----------
  __syncthreads();
  load_w128(p1_w, 256, 0, s_w, tid);
  __syncthreads();
  float hh0[2], hh1[2];
  {
    const float bp0 = p1_b[j0], bp1 = p1_b[j1];
    hh0[0] = hh0[1] = bp0; hh1[0] = hh1[1] = bp1;
    matvec_f32<2>(&s_cur[le0][0], 128, s_w, j0, hh0, hh1);
  }
  __syncthreads();
  load_w128(p1_w, 256, 128, s_w, tid);
  __syncthreads();
  {
    matvec_f32<2>(&s_agg[le0][0], 128, s_w, j0, hh0, hh1);
    const float pg0 = p1_g[j0], pg1 = p1_g[j1];
    const float pe0 = p1_be[j0], pe1 = p1_be[j1];
#pragma unroll
    for (int el = 0; el < 2; ++el) {
      wave_ln(hh0[el], hh1[el], pg0, pg1, pe0, pe1);
      hh0[el] = fmaxf(hh0[el], 0.f);
      hh1[el] = fmaxf(hh1[el], 0.f);
      s_ctx[le0 + el][j0] = hh0[el];   // reuse as h buffer
      s_ctx[le0 + el][j1] = hh1[el];
    }
  }

  // ---------- p2 + final LN + store ----------
  __syncthreads();
  load_w128(p2_w, 128, 0, s_w, tid);
  __syncthreads();
  {
    const float bo0 = p2_b[j0], bo1 = p2_b[j1];
    const float gg0 = p2_g[j0], gg1 = p2_g[j1];
    const float ee0 = p2_be[j0], ee1 = p2_be[j1];
    float y0[2], y1[2];
    y0[0] = y0[1] = bo0; y1[0] = y1[1] = bo1;
    matvec_f32<2>(&s_ctx[le0][0], 128, s_w, j0, y0, y1);
#pragma unroll
    for (int el = 0; el < 2; ++el) {
      wave_ln(y0[el], y1[el], gg0, gg1, ee0, ee1);
      out[(size_t)(ge0 + el) * 128 + j0] = y0[el];
      out[(size_t)(ge0 + el) * 128 + j1] = y1[el];
    }
  }
}

extern "C" void kernel_launch(void* const* d_in, const int* in_sizes, int n_in,
                              void* d_out, int out_size, void* d_ws, size_t ws_size,
                              hipStream_t stream) {
  const float* cur_x   = (const float*)d_in[0];
  const float* nb_x    = (const float*)d_in[1];
  const int*   nbm     = (const int*)d_in[2];
  const float* enc_w1  = (const float*)d_in[3];
  const float* enc_b1  = (const float*)d_in[4];
  const float* enc_g1  = (const float*)d_in[5];
  const float* enc_be1 = (const float*)d_in[6];
  const float* enc_w2  = (const float*)d_in[7];
  const float* enc_b2  = (const float*)d_in[8];
  const float* enc_g2  = (const float*)d_in[9];
  const float* enc_be2 = (const float*)d_in[10];
  const float* in_pw   = (const float*)d_in[11];
  const float* in_pb   = (const float*)d_in[12];
  const float* out_w   = (const float*)d_in[13];
  const float* out_b   = (const float*)d_in[14];
  const float* an_g    = (const float*)d_in[15];
  const float* an_b    = (const float*)d_in[16];
  const float* p1_w    = (const float*)d_in[17];
  const float* p1_b    = (const float*)d_in[18];
  const float* p1_g    = (const float*)d_in[19];
  const float* p1_be   = (const float*)d_in[20];
  const float* p2_w    = (const float*)d_in[21];
  const float* p2_b    = (const float*)d_in[22];
  const float* p2_g    = (const float*)d_in[23];
  const float* p2_be   = (const float*)d_in[24];
  float* out = (float*)d_out;

  const int B = in_sizes[0] / 16;       // 32768
  const int nblocks = B / TBE;          // 2048

  gcn_fused<<<nblocks, NTH, 0, stream>>>(
      cur_x, nb_x, nbm, enc_w1, enc_b1, enc_g1, enc_be1, enc_w2, enc_b2, enc_g2,
      enc_be2, in_pw, in_pb, out_w, out_b, an_g, an_b, p1_w, p1_b, p1_g, p1_be,
      p2_w, p2_b, p2_g, p2_be, out);
}

// Round 2
// 178.036 us; speedup vs baseline: 4.5790x; 4.5790x over previous
//
#include <hip/hip_runtime.h>

#define DEV __device__ __forceinline__

typedef __attribute__((ext_vector_type(8))) short bf16x8;
typedef __attribute__((ext_vector_type(4))) float f32x4;

static constexpr int NTH = 512;
static constexpr int TBE = 16;

// d_ws layout (bf16-element offsets)
static constexpr int W1P = 0;        // [128][32]  swz3 (K padded 16->32)
static constexpr int W2  = 4096;     // [128][128] swz7
static constexpr int WQ  = 20480;
static constexpr int WK  = 36864;
static constexpr int WVW = 53248;
static constexpr int OW  = 69632;
static constexpr int P1A = 86016;
static constexpr int P1B = 102400;
static constexpr int P2W = 118784;
static constexpr int WS_BF16_TOT = 135168;
static constexpr int NPRM = 18 * 128;
// param slots: 0 b1,1 g1,2 be1,3 b2,4 g2,5 be2,6 bq,7 bk,8 bv,9 out_b,
//              10 an_g,11 an_b,12 p1_b,13 p1_g,14 p1_be,15 p2_b,16 p2_g,17 p2_be

DEV unsigned short f2bf(float f) {
  unsigned u = __float_as_uint(f);
  return (unsigned short)((u + 0x7fffu + ((u >> 16) & 1u)) >> 16);
}

DEV void st_bf16(unsigned short* buf, int row, int col, float v) {
  buf[row * 128 + ((((col >> 3) ^ (row & 7)) << 3) | (col & 7))] = f2bf(v);
}
DEV float ld_bf16(const unsigned short* buf, int row, int col) {
  unsigned u = buf[row * 128 + ((((col >> 3) ^ (row & 7)) << 3) | (col & 7))];
  return __uint_as_float(u << 16);
}
DEV bf16x8 frag128(const unsigned short* buf, int row, int kk, int lg) {
  return *(const bf16x8*)(buf + row * 128 + (((kk * 4 + lg) ^ (row & 7)) << 3));
}
DEV bf16x8 frag32(const unsigned short* buf, int row, int lg) {
  return *(const bf16x8*)(buf + row * 32 + ((lg ^ (row & 3)) << 3));
}
DEV f32x4 mfma16(bf16x8 a, bf16x8 b, f32x4 c) {
  return __builtin_amdgcn_mfma_f32_16x16x32_bf16(a, b, c, 0, 0, 0);
}

// ---------------- prep: f32 weights -> pre-swizzled bf16 in d_ws ----------------
__global__ void prep(const float* __restrict__ enc_w1, const float* __restrict__ enc_w2,
                     const float* __restrict__ in_pw, const float* __restrict__ out_w,
                     const float* __restrict__ p1_w, const float* __restrict__ p2_w,
                     const float* __restrict__ enc_b1, const float* __restrict__ enc_g1,
                     const float* __restrict__ enc_be1, const float* __restrict__ enc_b2,
                     const float* __restrict__ enc_g2, const float* __restrict__ enc_be2,
                     const float* __restrict__ in_pb, const float* __restrict__ out_b,
                     const float* __restrict__ an_g, const float* __restrict__ an_b,
                     const float* __restrict__ p1_b, const float* __restrict__ p1_g,
                     const float* __restrict__ p1_be, const float* __restrict__ p2_b,
                     const float* __restrict__ p2_g, const float* __restrict__ p2_be,
                     unsigned short* __restrict__ wsb, float* __restrict__ wsp) {
  int t = blockIdx.x * blockDim.x + threadIdx.x;
  int NT = gridDim.x * blockDim.x;
  for (int i = t; i < 8 * 16384; i += NT) {
    int mi = i >> 14, e = i & 16383, row = e >> 7, col = e & 127;
    float v; int dstb;
    switch (mi) {
      case 0: v = enc_w2[row * 128 + col];         dstb = W2;  break;
      case 1: v = in_pw[row * 128 + col];          dstb = WQ;  break;
      case 2: v = in_pw[(128 + row) * 128 + col];  dstb = WK;  break;
      case 3: v = in_pw[(256 + row) * 128 + col];  dstb = WVW; break;
      case 4: v = out_w[row * 128 + col];          dstb = OW;  break;
      case 5: v = p1_w[row * 256 + col];           dstb = P1A; break;
      case 6: v = p1_w[row * 256 + 128 + col];     dstb = P1B; break;
      default: v = p2_w[row * 128 + col];          dstb = P2W; break;
    }
    wsb[dstb + row * 128 + ((((col >> 3) ^ (row & 7)) << 3) | (col & 7))] = f2bf(v);
  }
  for (int i = t; i < 4096; i += NT) {
    int row = i >> 5, col = i & 31;
    float v = (col < 16) ? enc_w1[row * 16 + col] : 0.f;
    wsb[W1P + row * 32 + ((((col >> 3) ^ (row & 3)) << 3) | (col & 7))] = f2bf(v);
  }
  for (int i = t; i < NPRM; i += NT) {
    int s = i >> 7, c = i & 127; float v;
    switch (s) {
      case 0: v = enc_b1[c]; break;  case 1: v = enc_g1[c]; break;
      case 2: v = enc_be1[c]; break; case 3: v = enc_b2[c]; break;
      case 4: v = enc_g2[c]; break;  case 5: v = enc_be2[c]; break;
      case 6: v = in_pb[c]; break;   case 7: v = in_pb[128 + c]; break;
      case 8: v = in_pb[256 + c]; break; case 9: v = out_b[c]; break;
      case 10: v = an_g[c]; break;   case 11: v = an_b[c]; break;
      case 12: v = p1_b[c]; break;   case 13: v = p1_g[c]; break;
      case 14: v = p1_be[c]; break;  case 15: v = p2_b[c]; break;
      case 16: v = p2_g[c]; break;   default: v = p2_be[c]; break;
    }
    wsp[i] = v;
  }
}

// ---------------- main fused kernel ----------------
__global__ __launch_bounds__(NTH, 1)
void gcn_mfma(const float* __restrict__ cur_x, const float* __restrict__ nb_x,
              const int* __restrict__ nb_mask,
              const unsigned short* __restrict__ wsb, const float* __restrict__ wsp,
              float* __restrict__ out) {
  __shared__ __align__(16) unsigned short s_stage[20480];  // 32KB main + 8KB w1p
  __shared__ __align__(16) unsigned short s_X[144 * 32];
  __shared__ __align__(16) unsigned short s_H[144 * 128];  // enc1-out, then k, then v
  __shared__ __align__(16) unsigned short s_Enb[128 * 128];
  __shared__ __align__(16) unsigned short s_Ecur[16 * 128];
  __shared__ __align__(16) float s_q[16 * 132];            // q, later f32 acc
  __shared__ __align__(16) float s_p[16 * 32];
  __shared__ __align__(16) unsigned short s_ctx[16 * 128];
  __shared__ __align__(16) unsigned short s_agg[16 * 128];
  __shared__ __align__(16) unsigned short s_hh[16 * 128];
  __shared__ float s_prm[NPRM];
  __shared__ int s_mask[16];

  const int tid = threadIdx.x;
  const int wv = tid >> 6, l = tid & 63, l15 = l & 15, lg = l >> 4;
  const int sub = l >> 5, l32 = l & 31;
  const int ebase = blockIdx.x * TBE;
  const int eo = wv * 2 + sub;     // element owned in per-element phases

  auto stage = [&](int srcOff) {
    const uint4* s = (const uint4*)(wsb + srcOff);
    uint4* d = (uint4*)s_stage;
#pragma unroll
    for (int i = 0; i < 4; ++i) d[tid + i * NTH] = s[tid + i * NTH];
  };

  // LN epilogue over a 16-row x 128-col tile held as vals[nt][reg] per lane.
  auto ln_epi = [&](float (&vals)[8][4], int bslot, int gslot, int beslot, bool relu) {
    float sm[4] = {0, 0, 0, 0}, sq[4] = {0, 0, 0, 0};
#pragma unroll
    for (int nt = 0; nt < 8; ++nt) {
      float b = s_prm[bslot * 128 + nt * 16 + l15];
#pragma unroll
      for (int r = 0; r < 4; ++r) {
        float v = vals[nt][r] + b; vals[nt][r] = v;
        sm[r] += v; sq[r] = fmaf(v, v, sq[r]);
      }
    }
#pragma unroll
    for (int off = 8; off >= 1; off >>= 1)
#pragma unroll
      for (int r = 0; r < 4; ++r) {
        sm[r] += __shfl_xor(sm[r], off);
        sq[r] += __shfl_xor(sq[r], off);
      }
    float mean[4], inv[4];
#pragma unroll
    for (int r = 0; r < 4; ++r) {
      mean[r] = sm[r] * 0.0078125f;
      float var = fmaf(sq[r], 0.0078125f, -mean[r] * mean[r]);
      inv[r] = rsqrtf(var + 1e-5f);
    }
#pragma unroll
    for (int nt = 0; nt < 8; ++nt) {
      int col = nt * 16 + l15;
      float g = s_prm[gslot * 128 + col], be = s_prm[beslot * 128 + col];
#pragma unroll
      for (int r = 0; r < 4; ++r) {
        float v = (vals[nt][r] - mean[r]) * inv[r] * g + be;
        vals[nt][r] = relu ? fmaxf(v, 0.f) : v;
      }
    }
  };

  // ---- load: params, w1p, inputs, masks ----
  {
    const uint4* s = (const uint4*)(wsb + W1P);
    ((uint4*)(s_stage + 16384))[tid] = s[tid];            // 8KB w1p
  }
  for (int i = tid; i < NPRM; i += NTH) s_prm[i] = wsp[i];
  for (int i = tid; i < 4608; i += NTH) {                 // X [144][32] padded
    int row = i >> 5, col = i & 31;
    int e = (row * 57) >> 9, kind = row - e * 9;
    float v = 0.f;
    if (col < 16) {
      int ge = ebase + e;
      v = (kind == 0) ? cur_x[(size_t)ge * 16 + col]
                      : nb_x[((size_t)ge * 8 + (kind - 1)) * 16 + col];
    }
    s_X[row * 32 + ((((col >> 3) ^ (row & 3)) << 3) | (col & 7))] = f2bf(v);
  }
  if (tid < 16) {
    int m = 0; const int* mp = nb_mask + (size_t)(ebase + tid) * 8;
#pragma unroll
    for (int n = 0; n < 8; ++n) m |= (mp[n] > 0) << n;
    s_mask[tid] = m;
  }
  __syncthreads();                                        // S1

  // ---- E1: X[144x32] @ w1p^T -> +b1,LN,ReLU -> s_H ----
  stage(W2);                                              // overlap w2 staging
  for (int mt = wv; mt < 9; mt += 8) {
    bf16x8 a = frag32(s_X, mt * 16 + l15, lg);
    float vals[8][4];
#pragma unroll
    for (int nt = 0; nt < 8; ++nt) {
      f32x4 acc = {0.f, 0.f, 0.f, 0.f};
      acc = mfma16(a, frag32(s_stage + 16384, nt * 16 + l15, lg), acc);
#pragma unroll
      for (int r = 0; r < 4; ++r) vals[nt][r] = acc[r];
    }
    ln_epi(vals, 0, 1, 2, true);
#pragma unroll
    for (int nt = 0; nt < 8; ++nt)
#pragma unroll
      for (int r = 0; r < 4; ++r)
        st_bf16(s_H, mt * 16 + lg * 4 + r, nt * 16 + l15, vals[nt][r]);
  }
  __syncthreads();                                        // S2

  // ---- E2: H @ w2^T -> +b2,LN -> Ecur/Enb ----
  for (int mt = wv; mt < 9; mt += 8) {
    bf16x8 a[4];
#pragma unroll
    for (int kk = 0; kk < 4; ++kk) a[kk] = frag128(s_H, mt * 16 + l15, kk, lg);
    float vals[8][4];
#pragma unroll
    for (int nt = 0; nt < 8; ++nt) {
      f32x4 acc = {0.f, 0.f, 0.f, 0.f};
#pragma unroll
      for (int kk = 0; kk < 4; ++kk)
        acc = mfma16(a[kk], frag128(s_stage, nt * 16 + l15, kk, lg), acc);
#pragma unroll
      for (int r = 0; r < 4; ++r) vals[nt][r] = acc[r];
    }
    ln_epi(vals, 3, 4, 5, false);
#pragma unroll
    for (int nt = 0; nt < 8; ++nt) {
      int col = nt * 16 + l15;
#pragma unroll
      for (int r = 0; r < 4; ++r) {
        int R = mt * 16 + lg * 4 + r;
        int e = (R * 57) >> 9, kind = R - e * 9;
        if (kind == 0) st_bf16(s_Ecur, e, col, vals[nt][r]);
        else           st_bf16(s_Enb, e * 8 + kind - 1, col, vals[nt][r]);
      }
    }
  }
  __syncthreads();                                        // S3
  stage(WQ);
  __syncthreads();                                        // S4

  // ---- Q GEMM ----
  {
    f32x4 acc = {0.f, 0.f, 0.f, 0.f};
#pragma unroll
    for (int kk = 0; kk < 4; ++kk)
      acc = mfma16(frag128(s_Ecur, l15, kk, lg), frag128(s_stage, wv * 16 + l15, kk, lg), acc);
    int col = wv * 16 + l15; float bq = s_prm[6 * 128 + col];
#pragma unroll
    for (int r = 0; r < 4; ++r) s_q[(lg * 4 + r) * 132 + col] = acc[r] + bq;
  }
  __syncthreads();                                        // S5
  stage(WK);
  __syncthreads();                                        // S6

  // ---- K GEMM: Enb @ wk^T + bk -> s_H (bf16) ----
  {
    bf16x8 b[4];
#pragma unroll
    for (int kk = 0; kk < 4; ++kk) b[kk] = frag128(s_stage, wv * 16 + l15, kk, lg);
    int col = wv * 16 + l15; float bk = s_prm[7 * 128 + col];
#pragma unroll
    for (int mt = 0; mt < 8; ++mt) {
      f32x4 acc = {0.f, 0.f, 0.f, 0.f};
#pragma unroll
      for (int kk = 0; kk < 4; ++kk)
        acc = mfma16(frag128(s_Enb, mt * 16 + l15, kk, lg), b[kk], acc);
#pragma unroll
      for (int r = 0; r < 4; ++r)
        st_bf16(s_H, mt * 16 + lg * 4 + r, col, acc[r] + bk);
    }
  }
  __syncthreads();                                        // S7

  // ---- scores + softmax (VALU) ----
  stage(WVW);                                             // overlap wv staging
  {
    int h = l32 >> 3, n = l32 & 7;
    int krow = eo * 8 + n;
    float dot = 0.f;
#pragma unroll
    for (int j = 0; j < 4; ++j) {
      bf16x8 kf = *(const bf16x8*)(s_H + krow * 128 + (((h * 4 + j) ^ (krow & 7)) << 3));
      const float* qp = s_q + eo * 132 + h * 32 + j * 8;
      float4 q0 = *(const float4*)qp, q1 = *(const float4*)(qp + 4);
      dot = fmaf(__uint_as_float(((unsigned)(unsigned short)kf[0]) << 16), q0.x, dot);
      dot = fmaf(__uint_as_float(((unsigned)(unsigned short)kf[1]) << 16), q0.y, dot);
      dot = fmaf(__uint_as_float(((unsigned)(unsigned short)kf[2]) << 16), q0.z, dot);
      dot = fmaf(__uint_as_float(((unsigned)(unsigned short)kf[3]) << 16), q0.w, dot);
      dot = fmaf(__uint_as_float(((unsigned)(unsigned short)kf[4]) << 16), q1.x, dot);
      dot = fmaf(__uint_as_float(((unsigned)(unsigned short)kf[5]) << 16), q1.y, dot);
      dot = fmaf(__uint_as_float(((unsigned)(unsigned short)kf[6]) << 16), q1.z, dot);
      dot = fmaf(__uint_as_float(((unsigned)(unsigned short)kf[7]) << 16), q1.w, dot);
    }
    float sc = dot * 0.17677669529663687f;
    int m = s_mask[eo];
    bool use = (m == 0) || ((m >> n) & 1);
    float scm = use ? sc : -1e30f;
    float mx = scm;
#pragma unroll
    for (int off = 4; off >= 1; off >>= 1) mx = fmaxf(mx, __shfl_xor(mx, off));
    float p = use ? __expf(sc - mx) : 0.f;
    float sum = p;
#pragma unroll
    for (int off = 4; off >= 1; off >>= 1) sum += __shfl_xor(sum, off);
    s_p[eo * 32 + h * 8 + n] = p / sum;
  }
  __syncthreads();                                        // S8

  // ---- V GEMM -> s_H (bf16) ----
  {
    bf16x8 b[4];
#pragma unroll
    for (int kk = 0; kk < 4; ++kk) b[kk] = frag128(s_stage, wv * 16 + l15, kk, lg);
    int col = wv * 16 + l15; float bv = s_prm[8 * 128 + col];
#pragma unroll
    for (int mt = 0; mt < 8; ++mt) {
      f32x4 acc = {0.f, 0.f, 0.f, 0.f};
#pragma unroll
      for (int kk = 0; kk < 4; ++kk)
        acc = mfma16(frag128(s_Enb, mt * 16 + l15, kk, lg), b[kk], acc);
#pragma unroll
      for (int r = 0; r < 4; ++r)
        st_bf16(s_H, mt * 16 + lg * 4 + r, col, acc[r] + bv);
    }
  }
  __syncthreads();                                        // S9

  // ---- ctx = P @ V (VALU) -> s_ctx ----
  stage(OW);                                              // overlap out_w staging
  {
#pragma unroll
    for (int cc = 0; cc < 4; ++cc) {
      int col = l32 + 32 * cc;
      float c = 0.f;
#pragma unroll
      for (int n = 0; n < 8; ++n)
        c = fmaf(s_p[eo * 32 + cc * 8 + n], ld_bf16(s_H, eo * 8 + n, col), c);
      st_bf16(s_ctx, eo, col, c);
    }
  }
  __syncthreads();                                        // S10

  // ---- OUT GEMM -> f32 acc in s_q ----
  {
    f32x4 acc = {0.f, 0.f, 0.f, 0.f};
#pragma unroll
    for (int kk = 0; kk < 4; ++kk)
      acc = mfma16(frag128(s_ctx, l15, kk, lg), frag128(s_stage, wv * 16 + l15, kk, lg), acc);
    int col = wv * 16 + l15; float bo = s_prm[9 * 128 + col];
#pragma unroll
    for (int r = 0; r < 4; ++r) s_q[(lg * 4 + r) * 132 + col] = acc[r] + bo;
  }
  __syncthreads();                                        // S11

  // ---- LN(an) + agg select -> s_agg ----
  stage(P1A);                                             // overlap p1a staging
  {
    float4 x = *(const float4*)&s_q[eo * 132 + l32 * 4];
    float s = x.x + x.y + x.z + x.w;
    float qq = fmaf(x.x, x.x, fmaf(x.y, x.y, fmaf(x.z, x.z, x.w * x.w)));
#pragma unroll
    for (int off = 16; off >= 1; off >>= 1) { s += __shfl_xor(s, off); qq += __shfl_xor(qq, off); }
    float mean = s * 0.0078125f;
    float var = fmaf(qq, 0.0078125f, -mean * mean);
    float inv = rsqrtf(var + 1e-5f);
    int m = s_mask[eo];
    float xa[4] = {x.x, x.y, x.z, x.w}, r4[4];
#pragma unroll
    for (int c = 0; c < 4; ++c) {
      int col = l32 * 4 + c;
      float v = (xa[c] - mean) * inv * s_prm[10 * 128 + col] + s_prm[11 * 128 + col];
      r4[c] = m ? v : ld_bf16(s_Ecur, eo, col);
    }
    uint2 uu;
    uu.x = (unsigned)f2bf(r4[0]) | ((unsigned)f2bf(r4[1]) << 16);
    uu.y = (unsigned)f2bf(r4[2]) | ((unsigned)f2bf(r4[3]) << 16);
    *(uint2*)(s_agg + eo * 128 + (((l32 >> 1) ^ (eo & 7)) << 3) + (l32 & 1) * 4) = uu;
  }
  __syncthreads();                                        // S12

  // ---- P1 = [cur|agg] @ p1_w^T : two K=128 halves, acc persists ----
  f32x4 accP = {0.f, 0.f, 0.f, 0.f};
#pragma unroll
  for (int kk = 0; kk < 4; ++kk)
    accP = mfma16(frag128(s_Ecur, l15, kk, lg), frag128(s_stage, wv * 16 + l15, kk, lg), accP);
  __syncthreads();                                        // S13
  stage(P1B);
  __syncthreads();                                        // S14
  {
#pragma unroll
    for (int kk = 0; kk < 4; ++kk)
      accP = mfma16(frag128(s_agg, l15, kk, lg), frag128(s_stage, wv * 16 + l15, kk, lg), accP);
    int col = wv * 16 + l15; float b = s_prm[12 * 128 + col];
#pragma unroll
    for (int r = 0; r < 4; ++r) s_q[(lg * 4 + r) * 132 + col] = accP[r] + b;
  }
  __syncthreads();                                        // S15

  // ---- LN(p1)+ReLU -> s_hh ----
  stage(P2W);                                             // overlap p2 staging
  {
    float4 x = *(const float4*)&s_q[eo * 132 + l32 * 4];
    float s = x.x + x.y + x.z + x.w;
    float qq = fmaf(x.x, x.x, fmaf(x.y, x.y, fmaf(x.z, x.z, x.w * x.w)));
#pragma unroll
    for (int off = 16; off >= 1; off >>= 1) { s += __shfl_xor(s, off); qq += __shfl_xor(qq, off); }
    float mean = s * 0.0078125f;
    float var = fmaf(qq, 0.0078125f, -mean * mean);
    float inv = rsqrtf(var + 1e-5f);
    float xa[4] = {x.x, x.y, x.z, x.w}, r4[4];
#pragma unroll
    for (int c = 0; c < 4; ++c) {
      int col = l32 * 4 + c;
      r4[c] = fmaxf((xa[c] - mean) * inv * s_prm[13 * 128 + col] + s_prm[14 * 128 + col], 0.f);
    }
    uint2 uu;
    uu.x = (unsigned)f2bf(r4[0]) | ((unsigned)f2bf(r4[1]) << 16);
    uu.y = (unsigned)f2bf(r4[2]) | ((unsigned)f2bf(r4[3]) << 16);
    *(uint2*)(s_hh + eo * 128 + (((l32 >> 1) ^ (eo & 7)) << 3) + (l32 & 1) * 4) = uu;
  }
  __syncthreads();                                        // S16

  // ---- P2 GEMM ----
  {
    f32x4 acc = {0.f, 0.f, 0.f, 0.f};
#pragma unroll
    for (int kk = 0; kk < 4; ++kk)
      acc = mfma16(frag128(s_hh, l15, kk, lg), frag128(s_stage, wv * 16 + l15, kk, lg), acc);
    int col = wv * 16 + l15; float b = s_prm[15 * 128 + col];
#pragma unroll
    for (int r = 0; r < 4; ++r) s_q[(lg * 4 + r) * 132 + col] = acc[r] + b;
  }
  __syncthreads();                                        // S17

  // ---- final LN -> global out ----
  {
    float4 x = *(const float4*)&s_q[eo * 132 + l32 * 4];
    float s = x.x + x.y + x.z + x.w;
    float qq = fmaf(x.x, x.x, fmaf(x.y, x.y, fmaf(x.z, x.z, x.w * x.w)));
#pragma unroll
    for (int off = 16; off >= 1; off >>= 1) { s += __shfl_xor(s, off); qq += __shfl_xor(qq, off); }
    float mean = s * 0.0078125f;
    float var = fmaf(qq, 0.0078125f, -mean * mean);
    float inv = rsqrtf(var + 1e-5f);
    float xa[4] = {x.x, x.y, x.z, x.w};
    float4 o;
    o.x = (xa[0] - mean) * inv * s_prm[16 * 128 + l32 * 4 + 0] + s_prm[17 * 128 + l32 * 4 + 0];
    o.y = (xa[1] - mean) * inv * s_prm[16 * 128 + l32 * 4 + 1] + s_prm[17 * 128 + l32 * 4 + 1];
    o.z = (xa[2] - mean) * inv * s_prm[16 * 128 + l32 * 4 + 2] + s_prm[17 * 128 + l32 * 4 + 2];
    o.w = (xa[3] - mean) * inv * s_prm[16 * 128 + l32 * 4 + 3] + s_prm[17 * 128 + l32 * 4 + 3];
    *(float4*)&out[(size_t)(ebase + eo) * 128 + l32 * 4] = o;
  }
}

extern "C" void kernel_launch(void* const* d_in, const int* in_sizes, int n_in,
                              void* d_out, int out_size, void* d_ws, size_t ws_size,
                              hipStream_t stream) {
  const float* cur_x   = (const float*)d_in[0];
  const float* nb_x    = (const float*)d_in[1];
  const int*   nbm     = (const int*)d_in[2];
  const float* enc_w1  = (const float*)d_in[3];
  const float* enc_b1  = (const float*)d_in[4];
  const float* enc_g1  = (const float*)d_in[5];
  const float* enc_be1 = (const float*)d_in[6];
  const float* enc_w2  = (const float*)d_in[7];
  const float* enc_b2  = (const float*)d_in[8];
  const float* enc_g2  = (const float*)d_in[9];
  const float* enc_be2 = (const float*)d_in[10];
  const float* in_pw   = (const float*)d_in[11];
  const float* in_pb   = (const float*)d_in[12];
  const float* out_w   = (const float*)d_in[13];
  const float* out_b   = (const float*)d_in[14];
  const float* an_g    = (const float*)d_in[15];
  const float* an_b    = (const float*)d_in[16];
  const float* p1_w    = (const float*)d_in[17];
  const float* p1_b    = (const float*)d_in[18];
  const float* p1_g    = (const float*)d_in[19];
  const float* p1_be   = (const float*)d_in[20];
  const float* p2_w    = (const float*)d_in[21];
  const float* p2_b    = (const float*)d_in[22];
  const float* p2_g    = (const float*)d_in[23];
  const float* p2_be   = (const float*)d_in[24];
  float* out = (float*)d_out;

  unsigned short* wsb = (unsigned short*)d_ws;
  float* wsp = (float*)(wsb + WS_BF16_TOT);

  prep<<<128, 256, 0, stream>>>(enc_w1, enc_w2, in_pw, out_w, p1_w, p2_w,
                                enc_b1, enc_g1, enc_be1, enc_b2, enc_g2, enc_be2,
                                in_pb, out_b, an_g, an_b, p1_b, p1_g, p1_be,
                                p2_b, p2_g, p2_be, wsb, wsp);

  const int B = in_sizes[0] / 16;
  gcn_mfma<<<B / TBE, NTH, 0, stream>>>(cur_x, nb_x, nbm, wsb, wsp, out);
}